// Round 1
// baseline (213.577 us; speedup 1.0000x reference)
//
#include <hip/hip_runtime.h>

#define E_EDGES 20000
#define D_DIM   128
#define HP      132           // 128 W2 rows + 1 bias row + 3 zero pad (for pipelined prefetch)

typedef __bf16 bf16x8 __attribute__((ext_vector_type(8)));
typedef float  floatx4 __attribute__((ext_vector_type(4)));

__device__ __forceinline__ unsigned short f32_to_bf16_rne(float f) {
    unsigned int u = __float_as_uint(f);
    unsigned int r = u + 0x7FFFu + ((u >> 16) & 1u);
    return (unsigned short)(r >> 16);
}

// ---------------------------------------------------------------------------
// Prep 1: build fragment-major B = W2 (plus b2 as h==128 row) in bf16.
// Chunk id c = (((h*4 + w)*2 + n)*4 + s)*64 + lane ; each chunk = 8 bf16 (16B)
// element j of chunk: B_h[k][col] = W2[h][col*128 + k],
//   col = 32w + 16n + (lane&15), k = 32s + 8*(lane>>4) + j
// ---------------------------------------------------------------------------
__global__ void prep_bpf(const float* __restrict__ W2, const float* __restrict__ b2,
                         uint4* __restrict__ bpf) {
    int c = blockIdx.x * 256 + threadIdx.x;
    if (c >= HP * 2048) return;
    int l = c & 63;
    int s = (c >> 6) & 3;
    int n = (c >> 8) & 1;
    int w = (c >> 9) & 3;
    int h = c >> 11;
    int col = 32 * w + 16 * n + (l & 15);
    int k0  = 32 * s + 8 * (l >> 4);
    union { unsigned short u16[8]; uint4 u4; } out;
    if (h < 128) {
        const float* src = W2 + (size_t)h * (D_DIM * D_DIM) + col * D_DIM + k0;
        #pragma unroll
        for (int j = 0; j < 8; ++j) out.u16[j] = f32_to_bf16_rne(src[j]);
    } else if (h == 128) {
        const float* src = b2 + col * D_DIM + k0;
        #pragma unroll
        for (int j = 0; j < 8; ++j) out.u16[j] = f32_to_bf16_rne(src[j]);
    } else {
        #pragma unroll
        for (int j = 0; j < 8; ++j) out.u16[j] = 0;
    }
    bpf[c] = out.u4;
}

// ---------------------------------------------------------------------------
// Prep 2: hiddenT[h][e] fp32. h<128: relu(ef@W1+b1); h==128: 1.0 (bias row);
// h in 129..131: 0.0 (pad rows -> contribute nothing).
// ---------------------------------------------------------------------------
__global__ void prep_hidden(const float* __restrict__ ef, const float* __restrict__ W1,
                            const float* __restrict__ b1, float* __restrict__ hT) {
    int e = blockIdx.x * 64 + (threadIdx.x & 63);
    int h = blockIdx.y * 4 + (threadIdx.x >> 6);
    if (e >= E_EDGES) return;
    float v;
    if (h < 128) {
        float acc = b1[h];
        #pragma unroll
        for (int k = 0; k < 16; ++k) acc += ef[e * 16 + k] * W1[k * 128 + h];
        v = fmaxf(acc, 0.0f);
    } else {
        v = (h == 128) ? 1.0f : 0.0f;
    }
    hT[(size_t)h * E_EDGES + e] = v;
}

// ---------------------------------------------------------------------------
// Prep 3: h_w fp32 -> bf16 (plain [e][j] layout).
// ---------------------------------------------------------------------------
__global__ void prep_hwbf(const float* __restrict__ hw, unsigned short* __restrict__ hwb) {
    int i = blockIdx.x * 256 + threadIdx.x;          // 4 elems per thread
    if (i >= (E_EDGES * D_DIM) / 4) return;
    const float4 v = ((const float4*)hw)[i];
    union { unsigned short u16[4]; uint2 u2; } o;
    o.u16[0] = f32_to_bf16_rne(v.x);
    o.u16[1] = f32_to_bf16_rne(v.y);
    o.u16[2] = f32_to_bf16_rne(v.z);
    o.u16[3] = f32_to_bf16_rne(v.w);
    ((uint2*)hwb)[i] = o.u2;
}

// ---------------------------------------------------------------------------
// Main: 250 blocks x 256 threads. Block = 80 edges x 128 cols.
// Wave w handles cols [32w, 32w+32): 5 m-tiles x 2 n-tiles of 16x16, K(j)=128.
// A (h_w frags, 80 VGPRs) resident across the whole h-loop.
// Per h: D = hw @ B_h via 40 MFMAs, then C += hiddenT[h][e] * D.
// ---------------------------------------------------------------------------
__global__ __launch_bounds__(256, 1)
void edge_main(const uint4* __restrict__ bpf, const float* __restrict__ hT,
               const uint4* __restrict__ hwb, float* __restrict__ out) {
    const int tid = threadIdx.x;
    const int w  = tid >> 6;
    const int l  = tid & 63;
    const int l4 = l >> 4;
    const int lm = l & 15;
    const int e0 = blockIdx.x * 80;

    // A fragments: A[m][s] = hw[e0+16m+lm][32s + 8*l4 .. +7]
    bf16x8 A[5][4];
    #pragma unroll
    for (int m = 0; m < 5; ++m)
        #pragma unroll
        for (int s = 0; s < 4; ++s)
            A[m][s] = ((const bf16x8*)hwb)[(e0 + 16 * m + lm) * 16 + 4 * s + l4];

    floatx4 C[5][2];
    #pragma unroll
    for (int m = 0; m < 5; ++m)
        #pragma unroll
        for (int n = 0; n < 2; ++n)
            C[m][n] = (floatx4){0.f, 0.f, 0.f, 0.f};
    floatx4 D[5][2];
    const floatx4 Zf = (floatx4){0.f, 0.f, 0.f, 0.f};

    bf16x8 Ba[2][4], Bb[2][4];
    floatx4 ha[5], hb[5];

    auto loadB = [&](int h, bf16x8 (&B)[2][4]) {
        const bf16x8* base = (const bf16x8*)bpf + (size_t)(h * 4 + w) * 512 + l;
        #pragma unroll
        for (int n = 0; n < 2; ++n)
            #pragma unroll
            for (int s = 0; s < 4; ++s)
                B[n][s] = base[(n * 4 + s) * 64];
    };
    auto loadH = [&](int h, floatx4 (&hq)[5]) {
        const float* row = hT + (size_t)h * E_EDGES + e0 + 4 * l4;
        #pragma unroll
        for (int m = 0; m < 5; ++m)
            hq[m] = *(const floatx4*)(row + 16 * m);
    };
    auto compute = [&](bf16x8 (&B)[2][4], floatx4 (&hq)[5]) {
        #pragma unroll
        for (int s = 0; s < 4; ++s)
            #pragma unroll
            for (int m = 0; m < 5; ++m)
                #pragma unroll
                for (int n = 0; n < 2; ++n)
                    D[m][n] = __builtin_amdgcn_mfma_f32_16x16x32_bf16(
                        A[m][s], B[n][s], (s == 0) ? Zf : D[m][n], 0, 0, 0);
        #pragma unroll
        for (int m = 0; m < 5; ++m)
            #pragma unroll
            for (int n = 0; n < 2; ++n) {
                #pragma unroll
                for (int r = 0; r < 4; ++r)
                    C[m][n][r] += hq[m][r] * D[m][n][r];
            }
    };

    loadB(0, Ba); loadH(0, ha);
    for (int h = 0; h < 130; h += 2) {
        loadB(h + 1, Bb); loadH(h + 1, hb);
        compute(Ba, ha);
        loadB(h + 2, Ba); loadH(h + 2, ha);   // h+2 <= 130 < HP: pad rows are zeros
        compute(Bb, hb);
    }

    // C/D layout: col = lane&15, row = 4*(lane>>4) + r
    #pragma unroll
    for (int m = 0; m < 5; ++m)
        #pragma unroll
        for (int n = 0; n < 2; ++n)
            #pragma unroll
            for (int r = 0; r < 4; ++r)
                out[(size_t)(e0 + 16 * m + 4 * l4 + r) * D_DIM + 32 * w + 16 * n + lm] = C[m][n][r];
}

// ---------------------------------------------------------------------------
extern "C" void kernel_launch(void* const* d_in, const int* in_sizes, int n_in,
                              void* d_out, int out_size, void* d_ws, size_t ws_size,
                              hipStream_t stream) {
    // inputs: h_v, h_w, edge_features, W1, b1, W2, b2  (all fp32; h_v unused by reference)
    const float* h_w = (const float*)d_in[1];
    const float* ef  = (const float*)d_in[2];
    const float* W1  = (const float*)d_in[3];
    const float* b1  = (const float*)d_in[4];
    const float* W2  = (const float*)d_in[5];
    const float* b2  = (const float*)d_in[6];
    float* out = (float*)d_out;

    char* ws = (char*)d_ws;
    uint4*          bpf = (uint4*)ws;                                   // HP*32768 = 4,325,376 B
    float*          hT  = (float*)(ws + 4325376);                       // HP*20000*4 = 10,560,000 B
    unsigned short* hwb = (unsigned short*)(ws + 4325376 + 10560000);   // 5,120,000 B
    // total ws use: 20,005,376 B

    hipLaunchKernelGGL(prep_bpf,    dim3((HP * 2048) / 256), dim3(256), 0, stream, W2, b2, bpf);
    hipLaunchKernelGGL(prep_hidden, dim3(313, 33),           dim3(256), 0, stream, ef, W1, b1, hT);
    hipLaunchKernelGGL(prep_hwbf,   dim3(2500),              dim3(256), 0, stream, h_w, hwb);
    hipLaunchKernelGGL(edge_main,   dim3(250),               dim3(256), 0, stream,
                       bpf, hT, (const uint4*)hwb, out);
}

// Round 2
// 192.217 us; speedup vs baseline: 1.1111x; 1.1111x over previous
//
#include <hip/hip_runtime.h>

#define E_EDGES 20000
#define D_DIM   128
#define HP      132           // 128 W2 rows + 1 bias row + 3 zero pad (pipelined prefetch)

// fused prep grid layout
#define NB_BPF  1056          // HP*2048/256 chunks
#define NB_HID  313           // ceil(20000/64) edge-blocks
#define NB_HWB  320           // grid-stride over 160000 uint2

typedef __bf16 bf16x8 __attribute__((ext_vector_type(8)));
typedef float  floatx4 __attribute__((ext_vector_type(4)));

__device__ __forceinline__ unsigned short f32_to_bf16_rne(float f) {
    unsigned int u = __float_as_uint(f);
    unsigned int r = u + 0x7FFFu + ((u >> 16) & 1u);
    return (unsigned short)(r >> 16);
}

// ---------------------------------------------------------------------------
// Fused prep:
//  part A (bx < NB_BPF): fragment-major bf16 B = W2 (+ b2 as h==128, pads 0).
//    chunk c = ((h*8 + g)*4 + s)*64 + lane ; 8 bf16 each.
//    elem j: B_h[k][col] = W2[h][col*128+k], col = 16g + (l&15),
//            k = 32s + 8*(l>>4) + j.   (per-wave reads: 16 cols x 128 B contig)
//  part B: hiddenT[h][e] fp32 via LDS-staged ef. h==128 -> 1.0, 129..131 -> 0.
//  part C: h_w fp32 -> bf16 [e][j].
// ---------------------------------------------------------------------------
__global__ __launch_bounds__(256) void prep_all(
    const float* __restrict__ W2, const float* __restrict__ b2,
    const float* __restrict__ ef, const float* __restrict__ W1,
    const float* __restrict__ b1, const float* __restrict__ hw,
    uint4* __restrict__ bpf, float* __restrict__ hT,
    unsigned short* __restrict__ hwb)
{
    __shared__ float lds_ef[64][17];
    const int bx = blockIdx.x;
    const int t  = threadIdx.x;

    if (bx < NB_BPF) {
        int c = bx * 256 + t;                 // exactly HP*2048 chunks
        int l = c & 63;
        int s = (c >> 6) & 3;
        int g = (c >> 8) & 7;
        int h = c >> 11;
        int col = 16 * g + (l & 15);
        int k0  = 32 * s + 8 * (l >> 4);
        union { unsigned short u16[8]; uint4 u4; } o;
        if (h < 128) {
            const float* src = W2 + (size_t)h * (D_DIM * D_DIM) + col * D_DIM + k0;
            #pragma unroll
            for (int j = 0; j < 8; ++j) o.u16[j] = f32_to_bf16_rne(src[j]);
        } else if (h == 128) {
            const float* src = b2 + col * D_DIM + k0;
            #pragma unroll
            for (int j = 0; j < 8; ++j) o.u16[j] = f32_to_bf16_rne(src[j]);
        } else {
            #pragma unroll
            for (int j = 0; j < 8; ++j) o.u16[j] = 0;
        }
        bpf[c] = o.u4;
    } else if (bx < NB_BPF + NB_HID) {
        const int b  = bx - NB_BPF;
        const int e0 = b * 64;
        {   // stage ef tile coalesced: thread t -> edge t/4, feature quad t%4
            int e  = t >> 2;
            int k4 = (t & 3) * 4;
            int ge = e0 + e;
            float4 v = make_float4(0.f, 0.f, 0.f, 0.f);
            if (ge < E_EDGES) v = *(const float4*)(ef + (size_t)ge * 16 + k4);
            lds_ef[e][k4 + 0] = v.x; lds_ef[e][k4 + 1] = v.y;
            lds_ef[e][k4 + 2] = v.z; lds_ef[e][k4 + 3] = v.w;
        }
        __syncthreads();
        const int e  = t & 63;
        const int hg = t >> 6;                // wave-uniform
        const bool valid = (e0 + e) < E_EDGES;
        float efr[16];
        #pragma unroll
        for (int k = 0; k < 16; ++k) efr[k] = lds_ef[e][k];
        #pragma unroll 4
        for (int hi = 0; hi < 32; ++hi) {
            int h = hg * 32 + hi;             // wave-uniform -> W1/b1 scalar loads
            float acc = b1[h];
            #pragma unroll
            for (int k = 0; k < 16; ++k) acc += efr[k] * W1[k * 128 + h];
            if (valid) hT[(size_t)h * E_EDGES + e0 + e] = fmaxf(acc, 0.f);
        }
        if (hg == 0 && valid) {
            hT[(size_t)128 * E_EDGES + e0 + e] = 1.0f;
            hT[(size_t)129 * E_EDGES + e0 + e] = 0.0f;
            hT[(size_t)130 * E_EDGES + e0 + e] = 0.0f;
            hT[(size_t)131 * E_EDGES + e0 + e] = 0.0f;
        }
    } else {
        int i0 = (bx - NB_BPF - NB_HID) * 256 + t;
        for (int i = i0; i < (E_EDGES * D_DIM) / 4; i += NB_HWB * 256) {
            const float4 v = ((const float4*)hw)[i];
            union { unsigned short u16[4]; uint2 u2; } o;
            o.u16[0] = f32_to_bf16_rne(v.x);
            o.u16[1] = f32_to_bf16_rne(v.y);
            o.u16[2] = f32_to_bf16_rne(v.z);
            o.u16[3] = f32_to_bf16_rne(v.w);
            ((uint2*)hwb)[i] = o.u2;
        }
    }
}

// ---------------------------------------------------------------------------
// Main: 504 blocks x 256 threads. Block = 80 edges x 64 cols (col-half ch).
// ch = (bx>>2)&1 -> XCDs 0-3 stream cols 0..63 of W2, XCDs 4-7 cols 64..127
// (per-XCD L2 working set 2.2 MB < 4 MiB). eg = (bx>>3)*4 + (bx&3).
// Wave w: 80 x 16 cols (col-group g = 4*ch + w): 5 m-tiles, n=1, 20 MFMA/h.
// A (h_w frags, 80 VGPRs) resident across the whole 130-step h-loop.
// VGPR ~190 -> 2 blocks/CU via __launch_bounds__(256,2).
// ---------------------------------------------------------------------------
__global__ __launch_bounds__(256, 2)
void edge_main(const uint4* __restrict__ bpf, const float* __restrict__ hT,
               const uint4* __restrict__ hwb, float* __restrict__ out) {
    const int bx = blockIdx.x;
    const int ch = (bx >> 2) & 1;
    const int eg = (bx >> 3) * 4 + (bx & 3);
    if (eg >= 250) return;
    const int tid = threadIdx.x;
    const int w  = tid >> 6;
    const int g  = 4 * ch + w;
    const int l  = tid & 63;
    const int l4 = l >> 4;
    const int lm = l & 15;
    const int e0 = eg * 80;

    // A fragments: A[m][s] = hw[e0+16m+lm][32s + 8*l4 .. +7]
    bf16x8 A[5][4];
    #pragma unroll
    for (int m = 0; m < 5; ++m)
        #pragma unroll
        for (int s = 0; s < 4; ++s)
            A[m][s] = ((const bf16x8*)hwb)[(e0 + 16 * m + lm) * 16 + 4 * s + l4];

    floatx4 C[5];
    #pragma unroll
    for (int m = 0; m < 5; ++m) C[m] = (floatx4){0.f, 0.f, 0.f, 0.f};
    floatx4 D[5];
    const floatx4 Zf = (floatx4){0.f, 0.f, 0.f, 0.f};

    bf16x8 Ba[4], Bb[4];
    floatx4 ha[5], hb[5];

    auto loadB = [&](int h, bf16x8 (&B)[4]) {
        const bf16x8* base = (const bf16x8*)bpf + ((size_t)(h * 8 + g) * 4) * 64 + l;
        #pragma unroll
        for (int s = 0; s < 4; ++s) B[s] = base[s * 64];
    };
    auto loadH = [&](int h, floatx4 (&hq)[5]) {
        const float* row = hT + (size_t)h * E_EDGES + e0 + 4 * l4;
        #pragma unroll
        for (int m = 0; m < 5; ++m) hq[m] = *(const floatx4*)(row + 16 * m);
    };
    auto compute = [&](bf16x8 (&B)[4], floatx4 (&hq)[5]) {
        #pragma unroll
        for (int s = 0; s < 4; ++s)
            #pragma unroll
            for (int m = 0; m < 5; ++m)
                D[m] = __builtin_amdgcn_mfma_f32_16x16x32_bf16(
                    A[m][s], B[s], (s == 0) ? Zf : D[m], 0, 0, 0);
        #pragma unroll
        for (int m = 0; m < 5; ++m)
            #pragma unroll
            for (int r = 0; r < 4; ++r)
                C[m][r] += hq[m][r] * D[m][r];
    };

    loadB(0, Ba); loadH(0, ha);
    for (int h = 0; h < 130; h += 2) {
        loadB(h + 1, Bb); loadH(h + 1, hb);
        compute(Ba, ha);
        loadB(h + 2, Ba); loadH(h + 2, ha);   // h+2 <= 130 < HP: pad rows are zeros
        compute(Bb, hb);
    }

    // C/D layout: col = lane&15, row = 4*(lane>>4) + r
    #pragma unroll
    for (int m = 0; m < 5; ++m)
        #pragma unroll
        for (int r = 0; r < 4; ++r)
            out[(size_t)(e0 + 16 * m + 4 * l4 + r) * D_DIM + 16 * g + lm] = C[m][r];
}

// ---------------------------------------------------------------------------
extern "C" void kernel_launch(void* const* d_in, const int* in_sizes, int n_in,
                              void* d_out, int out_size, void* d_ws, size_t ws_size,
                              hipStream_t stream) {
    // inputs: h_v, h_w, edge_features, W1, b1, W2, b2 (fp32; h_v unused)
    const float* h_w = (const float*)d_in[1];
    const float* ef  = (const float*)d_in[2];
    const float* W1  = (const float*)d_in[3];
    const float* b1  = (const float*)d_in[4];
    const float* W2  = (const float*)d_in[5];
    const float* b2  = (const float*)d_in[6];
    float* out = (float*)d_out;

    char* ws = (char*)d_ws;
    uint4*          bpf = (uint4*)ws;                                   // 4,325,376 B
    float*          hT  = (float*)(ws + 4325376);                       // 10,560,000 B
    unsigned short* hwb = (unsigned short*)(ws + 4325376 + 10560000);   // 5,120,000 B

    hipLaunchKernelGGL(prep_all, dim3(NB_BPF + NB_HID + NB_HWB), dim3(256), 0, stream,
                       W2, b2, ef, W1, b1, h_w, bpf, hT, hwb);
    hipLaunchKernelGGL(edge_main, dim3(504), dim3(256), 0, stream,
                       bpf, hT, (const uint4*)hwb, out);
}

// Round 3
// 185.403 us; speedup vs baseline: 1.1520x; 1.0368x over previous
//
#include <hip/hip_runtime.h>

#define E_EDGES 20000
#define D_DIM   128
#define NPAIRS  65            // h-pairs: (0,1)..(128,129); pair 64 = (bias, zero)
#define HSLICES 132           // bpf h-slices allocated (130 used)

// prep grid layout
#define NBA 130               // W2/b2 repack: one h-slice per block (128 W2 + bias + 1 zero)
#define NBH 313               // hidden: ceil(20000/64) edge-blocks
#define NBC 320               // h_w fp32->bf16, grid-stride

typedef __bf16 bf16x8 __attribute__((ext_vector_type(8)));
typedef float  floatx4 __attribute__((ext_vector_type(4)));

__device__ __forceinline__ unsigned short f32_to_bf16_rne(float f) {
    unsigned int u = __float_as_uint(f);
    unsigned int r = u + 0x7FFFu + ((u >> 16) & 1u);
    return (unsigned short)(r >> 16);
}

__device__ __forceinline__ void gload_lds16(const void* g, void* l) {
    __builtin_amdgcn_global_load_lds(
        (const __attribute__((address_space(1))) unsigned int*)g,
        (__attribute__((address_space(3))) unsigned int*)l, 16, 0, 0);
}

// ---------------------------------------------------------------------------
// Fused prep.
// Part A (bx < NBA): repack one h-slice of W2 (h==128: b2; h==129: zeros) into
//   fragment-major bf16 bpf via padded LDS transpose. Chunk layout within h:
//   cidx = (g*4+s)*64 + l; elem j: B_h[k][col], col = 16g + (l&15),
//   k = 32s + 8*(l>>4) + j.  Reads coalesced, writes coalesced.
// Part B: hiddenT bf16-PAIRS hTp[h2][e] = (bf16(hid[e,2h2]), bf16(hid[e,2h2+1])).
//   Row 64 = (1.0, 0) for the bias slice.
// Part C: h_w fp32 -> bf16 [e][j].
// ---------------------------------------------------------------------------
__global__ __launch_bounds__(256) void prep_all(
    const float* __restrict__ W2, const float* __restrict__ b2,
    const float* __restrict__ ef, const float* __restrict__ W1,
    const float* __restrict__ b1, const float* __restrict__ hw,
    uint4* __restrict__ bpf, unsigned int* __restrict__ hTp,
    unsigned short* __restrict__ hwb)
{
    __shared__ __align__(16) char pmem[34816];   // A: 128 x 136 ushort; B: 64 x 17 float
    const int bx = blockIdx.x;
    const int t  = threadIdx.x;

    if (bx < NBA) {
        const int h = bx;
        if (h < 129) {
            unsigned short* tile = (unsigned short*)pmem;   // [col][136]
            const float* src = (h < 128) ? (W2 + (size_t)h * (D_DIM * D_DIM)) : b2;
            #pragma unroll
            for (int r = 0; r < 16; ++r) {
                const float4 v = ((const float4*)src)[r * 256 + t];
                int c   = (r * 256 + t) * 4;
                int col = c >> 7;
                int k   = c & 127;
                unsigned int u0 = f32_to_bf16_rne(v.x) | ((unsigned int)f32_to_bf16_rne(v.y) << 16);
                unsigned int u1 = f32_to_bf16_rne(v.z) | ((unsigned int)f32_to_bf16_rne(v.w) << 16);
                *(uint2*)&tile[col * 136 + k] = make_uint2(u0, u1);
            }
            __syncthreads();
            #pragma unroll
            for (int r2 = 0; r2 < 8; ++r2) {
                int cidx = r2 * 256 + t;
                int g  = cidx >> 8;
                int s  = (cidx >> 6) & 3;
                int ll = cidx & 63;
                int col = 16 * g + (ll & 15);
                int k0  = 32 * s + 8 * (ll >> 4);
                bpf[(size_t)h * 2048 + cidx] = *(const uint4*)&tile[col * 136 + k0];
            }
        } else {
            #pragma unroll
            for (int r2 = 0; r2 < 8; ++r2)
                bpf[(size_t)h * 2048 + r2 * 256 + t] = make_uint4(0, 0, 0, 0);
        }
    } else if (bx < NBA + NBH) {
        float (*lds_ef)[17] = (float(*)[17])pmem;
        const int b  = bx - NBA;
        const int e0 = b * 64;
        {   // stage ef coalesced: thread t -> edge t/4, feature quad t%4
            int e  = t >> 2;
            int k4 = (t & 3) * 4;
            int ge = e0 + e;
            float4 v = make_float4(0.f, 0.f, 0.f, 0.f);
            if (ge < E_EDGES) v = *(const float4*)(ef + (size_t)ge * 16 + k4);
            lds_ef[e][k4 + 0] = v.x; lds_ef[e][k4 + 1] = v.y;
            lds_ef[e][k4 + 2] = v.z; lds_ef[e][k4 + 3] = v.w;
        }
        __syncthreads();
        const int e  = t & 63;
        const int hg = t >> 6;                // wave-uniform
        const bool valid = (e0 + e) < E_EDGES;
        float efr[16];
        #pragma unroll
        for (int k = 0; k < 16; ++k) efr[k] = lds_ef[e][k];
        #pragma unroll 4
        for (int hi2 = 0; hi2 < 16; ++hi2) {
            int h0 = hg * 32 + 2 * hi2;       // wave-uniform -> W1/b1 scalar loads
            float a0 = b1[h0], a1 = b1[h0 + 1];
            #pragma unroll
            for (int k = 0; k < 16; ++k) {
                a0 += efr[k] * W1[k * 128 + h0];
                a1 += efr[k] * W1[k * 128 + h0 + 1];
            }
            unsigned int pk = (unsigned int)f32_to_bf16_rne(fmaxf(a0, 0.f))
                            | ((unsigned int)f32_to_bf16_rne(fmaxf(a1, 0.f)) << 16);
            if (valid) hTp[(size_t)(hg * 16 + hi2) * E_EDGES + e0 + e] = pk;
        }
        if (hg == 0 && valid)
            hTp[(size_t)64 * E_EDGES + e0 + e] = 0x00003F80u;   // (bf16 1.0, bf16 0)
    } else {
        int i0 = (bx - NBA - NBH) * 256 + t;
        for (int i = i0; i < (E_EDGES * D_DIM) / 4; i += NBC * 256) {
            const float4 v = ((const float4*)hw)[i];
            union { unsigned short u16[4]; uint2 u2; } o;
            o.u16[0] = f32_to_bf16_rne(v.x);
            o.u16[1] = f32_to_bf16_rne(v.y);
            o.u16[2] = f32_to_bf16_rne(v.z);
            o.u16[3] = f32_to_bf16_rne(v.w);
            ((uint2*)hwb)[i] = o.u2;
        }
    }
}

// ---------------------------------------------------------------------------
// Main: 250 blocks x 512 threads (8 waves). Block = 160 edges x 64 cols.
// ch = bx&1 (per-XCD constant -> 2.16 MB B working set per XCD L2).
// Wave w: col-group g=w&3 (16 cols), edge-half eh=w>>2 (80 edges): 5 m-tiles.
// B staged per h-PAIR into LDS via global_load_lds (dbuf 2x32KB); frags via
// ds_read_b128. hidden as bf16 pairs, one dwordx4 per m per 2 h-steps.
// A (h_w frags, 80 VGPRs) resident across the whole loop.
// ---------------------------------------------------------------------------
__global__ __launch_bounds__(512, 2)
void edge_main(const uint4* __restrict__ bpf, const unsigned int* __restrict__ hTp,
               const uint4* __restrict__ hwb, float* __restrict__ out) {
    __shared__ __align__(16) char smem[65536];   // 2 x (2 x 16KB) B pair-buffers
    const int bx  = blockIdx.x;
    const int ch  = bx & 1;
    const int eg  = bx >> 1;                      // 0..124
    const int tid = threadIdx.x;
    const int w   = tid >> 6;
    const int l   = tid & 63;
    const int l4  = l >> 4;
    const int lm  = l & 15;
    const int g   = w & 3;
    const int eh  = w >> 2;
    const int e0  = eg * 160;
    const int eA  = e0 + eh * 80;

    // resident A frags: A[m][s] = hw[eA+16m+lm][32s+8*l4 .. +7]
    bf16x8 A[5][4];
    #pragma unroll
    for (int m = 0; m < 5; ++m)
        #pragma unroll
        for (int s = 0; s < 4; ++s)
            A[m][s] = ((const bf16x8*)hwb)[(eA + 16 * m + lm) * 16 + 4 * s + l4];

    floatx4 C[5];
    #pragma unroll
    for (int m = 0; m < 5; ++m) C[m] = (floatx4){0.f, 0.f, 0.f, 0.f};
    const floatx4 Zf = (floatx4){0.f, 0.f, 0.f, 0.f};

    const char* bpf_c = (const char*)bpf;

    auto stage = [&](int pair, int p) {           // stage both h-slices of a pair
        #pragma unroll
        for (int hh = 0; hh < 2; ++hh) {
            const int h = 2 * pair + hh;
            const char* src = bpf_c + ((size_t)(h * 8 + 4 * ch) * 256) * 16;
            char* dst = smem + p * 32768 + hh * 16384;
            #pragma unroll
            for (int r = 0; r < 2; ++r) {
                const int off = (r * 512 + w * 64) * 16;   // wave-uniform LDS base
                gload_lds16(src + off + l * 16, dst + off);
            }
        }
    };
    auto loadHP = [&](int pair, uint4 (&hp)[5]) {
        const unsigned int* row = hTp + (size_t)pair * E_EDGES + eA + 4 * l4;
        #pragma unroll
        for (int m = 0; m < 5; ++m) hp[m] = *(const uint4*)(row + 16 * m);
    };
    auto computeH = [&](int p, int hh, const uint4 (&hp)[5], bool odd) {
        const bf16x8* Bb = (const bf16x8*)(smem + p * 32768 + hh * 16384) + g * 256 + l;
        bf16x8 B[4];
        #pragma unroll
        for (int s = 0; s < 4; ++s) B[s] = Bb[s * 64];
        #pragma unroll
        for (int m = 0; m < 5; ++m) {
            floatx4 D = __builtin_amdgcn_mfma_f32_16x16x32_bf16(A[m][0], B[0], Zf, 0, 0, 0);
            #pragma unroll
            for (int s = 1; s < 4; ++s)
                D = __builtin_amdgcn_mfma_f32_16x16x32_bf16(A[m][s], B[s], D, 0, 0, 0);
            #pragma unroll
            for (int r = 0; r < 4; ++r) {
                unsigned int u = hp[m][r];
                float sc = odd ? __uint_as_float(u & 0xFFFF0000u)
                               : __uint_as_float(u << 16);
                C[m][r] += sc * D[r];
            }
        }
    };

    uint4 hpa[5], hpb[5];
    stage(0, 0);
    loadHP(0, hpa);
    for (int pr = 0; pr < 64; pr += 2) {
        __syncthreads();                 // pair pr staged (buf0) + prior reads done
        stage(pr + 1, 1);
        loadHP(pr + 1, hpb);
        computeH(0, 0, hpa, false);
        computeH(0, 1, hpa, true);
        __syncthreads();                 // pair pr+1 staged (buf1)
        stage(pr + 2, 0);
        loadHP(pr + 2, hpa);
        computeH(1, 0, hpb, false);
        computeH(1, 1, hpb, true);
    }
    __syncthreads();                     // pair 64 staged (buf0)
    computeH(0, 0, hpa, false);          // h=128: bias row (hidden scale = 1.0)
    computeH(0, 1, hpa, true);           // h=129: zero row (scale 0 x zero B)

    // epilogue: C/D layout col = lane&15, row = 4*(lane>>4) + r
    #pragma unroll
    for (int m = 0; m < 5; ++m)
        #pragma unroll
        for (int r = 0; r < 4; ++r)
            out[(size_t)(eA + 16 * m + 4 * l4 + r) * D_DIM + 64 * ch + 16 * g + lm] = C[m][r];
}

// ---------------------------------------------------------------------------
extern "C" void kernel_launch(void* const* d_in, const int* in_sizes, int n_in,
                              void* d_out, int out_size, void* d_ws, size_t ws_size,
                              hipStream_t stream) {
    // inputs: h_v, h_w, edge_features, W1, b1, W2, b2 (fp32; h_v unused)
    const float* h_w = (const float*)d_in[1];
    const float* ef  = (const float*)d_in[2];
    const float* W1  = (const float*)d_in[3];
    const float* b1  = (const float*)d_in[4];
    const float* W2  = (const float*)d_in[5];
    const float* b2  = (const float*)d_in[6];
    float* out = (float*)d_out;

    char* ws = (char*)d_ws;
    uint4*          bpf = (uint4*)ws;                                  // 132*32768 = 4,325,376 B
    unsigned int*   hTp = (unsigned int*)(ws + 4325376);               // 65*20000*4 = 5,200,000 B
    unsigned short* hwb = (unsigned short*)(ws + 4325376 + 5200000);   // 5,120,000 B
    // total ws use: 14,645,376 B

    hipLaunchKernelGGL(prep_all, dim3(NBA + NBH + NBC), dim3(256), 0, stream,
                       W2, b2, ef, W1, b1, h_w, bpf, hTp, hwb);
    hipLaunchKernelGGL(edge_main, dim3(250), dim3(512), 0, stream,
                       bpf, hTp, (const uint4*)hwb, out);
}